// Round 2
// baseline (138.815 us; speedup 1.0000x reference)
//
#include <hip/hip_runtime.h>
#include <math.h>

typedef _Float16 half8  __attribute__((ext_vector_type(8)));
typedef _Float16 half4v __attribute__((ext_vector_type(4)));
typedef float    floatx4 __attribute__((ext_vector_type(4)));

#define NTOK   4096      // 128*32 tokens per side
#define DDIM   256
#define LPITCH 72        // 64 + 8 halves (16B pad) -> <=2-way LDS bank aliasing (free)

// ---------------------------------------------------------------- fp32 -> fp16
// One kernel for both q and t: blocks [0,1024) -> q, [1024,2048) -> t.
__global__ void cvt_fp16(const float* __restrict__ q, const float* __restrict__ t,
                         _Float16* __restrict__ Qh, _Float16* __restrict__ Th) {
    int b = blockIdx.x;
    const float* src = (b < 1024) ? q : t;
    _Float16*    dst = (b < 1024) ? Qh : Th;
    int base = ((b < 1024) ? b : b - 1024) * 1024;
    int i = base + threadIdx.x * 4;
    float4 v = *(const float4*)(src + i);
    half4v h;
    h[0] = (_Float16)v.x; h[1] = (_Float16)v.y; h[2] = (_Float16)v.z; h[3] = (_Float16)v.w;
    *(half4v*)(dst + i) = h;
}

// ------------------------------------------------- per-token vMF scalar stats
// One wave per 32-token row; 256 rows total (rows [0,128): q-batches,
// rows [128,256): t-targets). All float math:
//   lgamma(k+1)+lgamma(k+128) = 491.553448... + prefix_sum_{j<=k}[log j + log(j+127)]
// computed by a 6-step __shfl_up scan (no doubles, no serial chain). Per token,
// lanes 0..49 hold the 50 series terms; logsumexp via 6-step butterflies.
// For q-rows, the wave also computes the token-weight softmax in-register.
__global__ void vmf_stats(const float* __restrict__ kq, const float* __restrict__ kt,
                          float* __restrict__ Apq, float* __restrict__ kqc, float* __restrict__ uq,
                          float* __restrict__ wq,
                          float* __restrict__ At,  float* __restrict__ ktc, float* __restrict__ vt,
                          float* __restrict__ ent_out) {
    int lane = threadIdx.x;          // block = 1 wave of 64
    int row  = blockIdx.x;           // 0..255
    bool isQ = row < 128;
    const float* ksrc = isQ ? (kq + row * 32) : (kt + (row - 128) * 32);

    // --- series constants, lane-parallel
    float a = 0.f;
    if (lane >= 1 && lane < 50) a = logf((float)lane) + logf((float)(lane + 127));
    #pragma unroll
    for (int off = 1; off < 64; off <<= 1) {
        float tmp = __shfl_up(a, off, 64);
        if (lane >= off) a += tmp;
    }
    const float slg   = 491.5534482233f + a;        // lgamma(k+1)+lgamma(k+128)
    const float lk128 = logf((float)(lane + 128));  // log(k+128)
    const float c0k   = (float)(2 * lane + 127);
    const float c1k   = (float)(2 * lane + 128);
    const bool  valid = lane < 50;

    float entv = 0.f, Av = 0.f, kapv = 0.f;
    for (int i = 0; i < 32; ++i) {
        float kap  = fmaxf(ksrc[i], 1e-6f);
        float lkap = logf(kap);
        float lx   = lkap - 0.6931471805599453f;    // log(kap/2)
        float lc0 = valid ? c0k * lx - slg         : -INFINITY;
        float lc1 = valid ? c1k * lx - slg - lk128 : -INFINITY;
        float m0 = lc0, m1 = lc1;
        #pragma unroll
        for (int off = 1; off < 64; off <<= 1) {
            m0 = fmaxf(m0, __shfl_xor(m0, off, 64));
            m1 = fmaxf(m1, __shfl_xor(m1, off, 64));
        }
        float e0 = valid ? expf(lc0 - m0) : 0.f;
        float e1 = valid ? expf(lc1 - m1) : 0.f;
        #pragma unroll
        for (int off = 1; off < 64; off <<= 1) {
            e0 += __shfl_xor(e0, off, 64);
            e1 += __shfl_xor(e1, off, 64);
        }
        float logI0 = m0 + logf(e0);   // log I_127(kap)
        float logI1 = m1 + logf(e1);   // log I_128(kap)

        float A = expf(fminf(fmaxf(logI1 - logI0, -60.f), 0.f));
        A = fminf(fmaxf(A, 1e-8f), 1.f - 1e-6f);
        float logC = 127.f * lkap - 235.2482644983962f - logI0;  // 128*log(2pi)
        float e = -logC - kap * A;
        if (lane == i) { entv = e; Av = A; kapv = kap; }
    }

    int tok = (isQ ? row : row - 128) * 32 + lane;  // lanes 0..31 write
    if (isQ) {
        // token-weight softmax over the 32 entropies (lanes 0..31)
        float x = (lane < 32) ? -2.0f * entv : -INFINITY;
        float m = x;
        #pragma unroll
        for (int off = 1; off < 64; off <<= 1) m = fmaxf(m, __shfl_xor(m, off, 64));
        float p = (lane < 32) ? expf(x - m) : 0.f;
        float s = p;
        #pragma unroll
        for (int off = 1; off < 64; off <<= 1) s += __shfl_xor(s, off, 64);
        if (lane < 32) {
            Apq[tok] = Av; kqc[tok] = kapv; uq[tok] = -0.5f * Av * kapv;
            wq[tok] = p / s;
            ent_out[tok] = entv;
        }
    } else {
        if (lane < 32) {
            At[tok] = Av; ktc[tok] = kapv; vt[tok] = -0.5f * Av * kapv;
        }
    }
}

// --------------------------------------------------- fused GEMM + vMF epilogue
// (unchanged from the passing Round-1 kernel)
__global__ void __launch_bounds__(256)
gemm_score(const _Float16* __restrict__ Qh, const _Float16* __restrict__ Th,
           const float* __restrict__ Apq, const float* __restrict__ kqc,
           const float* __restrict__ uq,  const float* __restrict__ wq,
           const float* __restrict__ At,  const float* __restrict__ ktc,
           const float* __restrict__ vt,  float* __restrict__ score_out) {
    __shared__ _Float16 Qs[128 * LPITCH];
    __shared__ _Float16 Ts[128 * LPITCH];
    int tid = threadIdx.x;
    int lane = tid & 63, wave = tid >> 6;
    int wr = wave >> 1, wc = wave & 1;
    int bx = blockIdx.x, by = blockIdx.y;

    floatx4 acc[4][4];
    #pragma unroll
    for (int i = 0; i < 4; ++i)
        #pragma unroll
        for (int j = 0; j < 4; ++j)
            acc[i][j] = (floatx4){0.f, 0.f, 0.f, 0.f};

    int l15 = lane & 15, lq = lane >> 4;

    for (int kk = 0; kk < 4; ++kk) {
        __syncthreads();
        #pragma unroll
        for (int it = 0; it < 4; ++it) {
            int s = it * 256 + tid;
            int r = s >> 3, c = s & 7;
            *(uint4*)(Qs + r * LPITCH + c * 8) =
                *(const uint4*)(Qh + (size_t)(by * 128 + r) * DDIM + kk * 64 + c * 8);
            *(uint4*)(Ts + r * LPITCH + c * 8) =
                *(const uint4*)(Th + (size_t)(bx * 128 + r) * DDIM + kk * 64 + c * 8);
        }
        __syncthreads();
        #pragma unroll
        for (int ks = 0; ks < 2; ++ks) {
            half8 a[4], b[4];
            int ko = ks * 32 + lq * 8;
            #pragma unroll
            for (int i = 0; i < 4; ++i)
                a[i] = *(const half8*)(Qs + (wr * 64 + i * 16 + l15) * LPITCH + ko);
            #pragma unroll
            for (int j = 0; j < 4; ++j)
                b[j] = *(const half8*)(Ts + (wc * 64 + j * 16 + l15) * LPITCH + ko);
            #pragma unroll
            for (int i = 0; i < 4; ++i)
                #pragma unroll
                for (int j = 0; j < 4; ++j)
                    acc[i][j] = __builtin_amdgcn_mfma_f32_16x16x32_f16(a[i], b[j], acc[i][j], 0, 0, 0);
        }
    }

    int colbase = bx * 128 + wc * 64 + l15;
    int rowbase = by * 128 + wr * 64 + lq * 4;
    #pragma unroll
    for (int bi = 0; bi < 2; ++bi) {
        #pragma unroll
        for (int bj = 0; bj < 2; ++bj) {
            float part = 0.f;
            #pragma unroll
            for (int ii = 0; ii < 2; ++ii) {
                int i  = bi * 2 + ii;
                int rg = rowbase + i * 16;
                float mx[4] = {-INFINITY, -INFINITY, -INFINITY, -INFINITY};
                #pragma unroll
                for (int jj = 0; jj < 2; ++jj) {
                    int j  = bj * 2 + jj;
                    int cg = colbase + j * 16;
                    float at_ = At[cg], kt_ = ktc[cg], v_ = vt[cg];
                    floatx4 sim = acc[i][j];
                    #pragma unroll
                    for (int rr = 0; rr < 4; ++rr) {
                        float sc = uq[rg + rr] + v_ +
                                   0.5f * (Apq[rg + rr] * kt_ + at_ * kqc[rg + rr]) * sim[rr];
                        mx[rr] = fmaxf(mx[rr], sc);
                    }
                }
                #pragma unroll
                for (int msk = 1; msk <= 8; msk <<= 1)
                    #pragma unroll
                    for (int rr = 0; rr < 4; ++rr)
                        mx[rr] = fmaxf(mx[rr], __shfl_xor(mx[rr], msk, 64));
                if (l15 == 0) {
                    #pragma unroll
                    for (int rr = 0; rr < 4; ++rr)
                        part += wq[rg + rr] * mx[rr];
                }
            }
            part += __shfl_xor(part, 16, 64);
            part += __shfl_xor(part, 32, 64);
            if (lane == 0) {
                int b = by * 4 + wr * 2 + bi;
                int n = bx * 4 + wc * 2 + bj;
                score_out[b * 128 + n] = part;
            }
        }
    }
}

// ------------------------------------------- logits, log-softmax over n, loss
// Single block, 128 threads (one per row). Score staged through LDS with a
// +1 pad (bank = (b+j)%32 -> 2-way within a wave = free). No atomics/memset.
__global__ void softmax_loss(const float* __restrict__ score, const float* __restrict__ temp_p,
                             float* __restrict__ logits, float* __restrict__ loss) {
    __shared__ float sc[128 * 129];
    __shared__ float part[2];
    int tid = threadIdx.x;    // 0..127
    float temp = fmaxf(temp_p[0], 1e-6f);
    float inv = 1.0f / temp;

    // coalesced stage: 16384 floats, float4 per thread per iter
    for (int idx = tid; idx < 4096; idx += 128) {
        float4 v = *(const float4*)(score + idx * 4);
        int r = (idx * 4) >> 7, c = (idx * 4) & 127;
        float* p = sc + r * 129 + c;
        p[0] = v.x; p[1] = v.y; p[2] = v.z; p[3] = v.w;
    }
    __syncthreads();

    int b = tid;
    float m = -INFINITY;
    for (int j = 0; j < 128; ++j) m = fmaxf(m, sc[b * 129 + j] * inv);
    float s = 0.f;
    for (int j = 0; j < 128; ++j) s += expf(sc[b * 129 + j] * inv - m);
    float lse = m + logf(s);
    float le  = lse - sc[b * 129 + b] * inv;

    // coalesced logits write
    for (int idx = tid; idx < 4096; idx += 128) {
        int r = (idx * 4) >> 7, c = (idx * 4) & 127;
        float* p = sc + r * 129 + c;
        float4 v = {p[0] * inv, p[1] * inv, p[2] * inv, p[3] * inv};
        *(float4*)(logits + idx * 4) = v;
    }

    // mean over 128 rows
    float x = le;
    #pragma unroll
    for (int off = 1; off < 64; off <<= 1) x += __shfl_xor(x, off, 64);
    if ((tid & 63) == 0) part[tid >> 6] = x;
    __syncthreads();
    if (tid == 0) loss[0] = (part[0] + part[1]) * (1.0f / 128.0f);
}

// ---------------------------------------------------------------------- launch
extern "C" void kernel_launch(void* const* d_in, const int* in_sizes, int n_in,
                              void* d_out, int out_size, void* d_ws, size_t ws_size,
                              hipStream_t stream) {
    const float* q    = (const float*)d_in[0];   // (128,32,256)
    const float* kq   = (const float*)d_in[1];   // (128,32)
    const float* t    = (const float*)d_in[2];   // (128,32,256)
    const float* kt   = (const float*)d_in[3];   // (128,32)
    const float* temp = (const float*)d_in[4];   // scalar

    float* out    = (float*)d_out;
    float* loss   = out;                 // [1]
    float* logits = out + 1;             // [128*128]
    float* score  = out + 1 + 16384;     // [128*128]
    float* ent    = out + 1 + 32768;     // [128*32]

    char* ws = (char*)d_ws;
    _Float16* Qh = (_Float16*)(ws);
    _Float16* Th = (_Float16*)(ws + (1 << 21));
    float* stats = (float*)(ws + (1 << 22));
    float *Apq = stats,          *kqc = stats + 4096, *uq = stats + 8192,
          *wq  = stats + 12288,  *At  = stats + 16384, *ktc = stats + 20480,
          *vt  = stats + 24576;

    cvt_fp16<<<2048, 256, 0, stream>>>(q, t, Qh, Th);
    vmf_stats<<<256, 64, 0, stream>>>(kq, kt, Apq, kqc, uq, wq, At, ktc, vt, ent);
    dim3 g(32, 32);
    gemm_score<<<g, 256, 0, stream>>>(Qh, Th, Apq, kqc, uq, wq, At, ktc, vt, score);
    softmax_loss<<<1, 128, 0, stream>>>(score, temp, logits, loss);
}

// Round 3
// 129.568 us; speedup vs baseline: 1.0714x; 1.0714x over previous
//
#include <hip/hip_runtime.h>
#include <math.h>

typedef _Float16 half8  __attribute__((ext_vector_type(8)));
typedef _Float16 half4v __attribute__((ext_vector_type(4)));
typedef float    floatx4 __attribute__((ext_vector_type(4)));

#define DDIM 256

// async global->LDS, 16B per lane; LDS dest = wave-uniform base + lane*16
#define GLOAD_LDS16(g, l) \
    __builtin_amdgcn_global_load_lds((const __attribute__((address_space(1))) void*)(g), \
                                     (__attribute__((address_space(3))) void*)(l), 16, 0, 0)

// ------------------------------------------------------------ fused prep
// blocks [0,2048): fp32->fp16 convert of q (first 1024) and t (next 1024)
// blocks [2048,2112): per-token vMF stats, 4 waves/block, one 32-token row/wave.
//   lgamma(k+1)+lgamma(k+128) = lgamma(128) + prefix_sum_{j<=k}[log j + log(j+127)]
//   via 6-step __shfl_up scan; 50 series terms on lanes 0..49; logsumexp via
//   butterflies. q-rows also compute the token-weight softmax in-register.
__global__ void prep(const float* __restrict__ q, const float* __restrict__ t,
                     _Float16* __restrict__ Qh, _Float16* __restrict__ Th,
                     const float* __restrict__ kq, const float* __restrict__ kt,
                     float* __restrict__ Apq, float* __restrict__ kqc, float* __restrict__ uq,
                     float* __restrict__ wq,
                     float* __restrict__ At,  float* __restrict__ ktc, float* __restrict__ vt,
                     float* __restrict__ ent_out) {
    int b = blockIdx.x;
    if (b < 2048) {
        const float* src = (b < 1024) ? q : t;
        _Float16*    dst = (b < 1024) ? Qh : Th;
        int i = ((b & 1023) * 1024) + threadIdx.x * 4;
        float4 v = *(const float4*)(src + i);
        half4v h;
        h[0] = (_Float16)v.x; h[1] = (_Float16)v.y; h[2] = (_Float16)v.z; h[3] = (_Float16)v.w;
        *(half4v*)(dst + i) = h;
        return;
    }
    int lane = threadIdx.x & 63;
    int row  = (b - 2048) * 4 + (threadIdx.x >> 6);   // 0..255
    bool isQ = row < 128;
    const float* ksrc = isQ ? (kq + row * 32) : (kt + (row - 128) * 32);

    float a = 0.f;
    if (lane >= 1 && lane < 50) a = logf((float)lane) + logf((float)(lane + 127));
    #pragma unroll
    for (int off = 1; off < 64; off <<= 1) {
        float tmp = __shfl_up(a, off, 64);
        if (lane >= off) a += tmp;
    }
    const float slg   = 491.5534482233f + a;        // lgamma(k+1)+lgamma(k+128)
    const float lk128 = logf((float)(lane + 128));  // log(k+128)
    const float c0k   = (float)(2 * lane + 127);
    const float c1k   = (float)(2 * lane + 128);
    const bool  valid = lane < 50;

    float entv = 0.f, Av = 0.f, kapv = 0.f;
    for (int i = 0; i < 32; ++i) {
        float kap  = fmaxf(ksrc[i], 1e-6f);
        float lkap = logf(kap);
        float lx   = lkap - 0.6931471805599453f;    // log(kap/2)
        float lc0 = valid ? c0k * lx - slg         : -INFINITY;
        float lc1 = valid ? c1k * lx - slg - lk128 : -INFINITY;
        float m0 = lc0, m1 = lc1;
        #pragma unroll
        for (int off = 1; off < 64; off <<= 1) {
            m0 = fmaxf(m0, __shfl_xor(m0, off, 64));
            m1 = fmaxf(m1, __shfl_xor(m1, off, 64));
        }
        float e0 = valid ? expf(lc0 - m0) : 0.f;
        float e1 = valid ? expf(lc1 - m1) : 0.f;
        #pragma unroll
        for (int off = 1; off < 64; off <<= 1) {
            e0 += __shfl_xor(e0, off, 64);
            e1 += __shfl_xor(e1, off, 64);
        }
        float logI0 = m0 + logf(e0);   // log I_127(kap)
        float logI1 = m1 + logf(e1);   // log I_128(kap)

        float A = expf(fminf(fmaxf(logI1 - logI0, -60.f), 0.f));
        A = fminf(fmaxf(A, 1e-8f), 1.f - 1e-6f);
        float logC = 127.f * lkap - 235.2482644983962f - logI0;  // 128*log(2pi)
        float e = -logC - kap * A;
        if (lane == i) { entv = e; Av = A; kapv = kap; }
    }

    int tok = (isQ ? row : row - 128) * 32 + lane;
    if (isQ) {
        float x = (lane < 32) ? -2.0f * entv : -INFINITY;
        float m = x;
        #pragma unroll
        for (int off = 1; off < 64; off <<= 1) m = fmaxf(m, __shfl_xor(m, off, 64));
        float p = (lane < 32) ? expf(x - m) : 0.f;
        float s = p;
        #pragma unroll
        for (int off = 1; off < 64; off <<= 1) s += __shfl_xor(s, off, 64);
        if (lane < 32) {
            Apq[tok] = Av; kqc[tok] = kapv; uq[tok] = -0.5f * Av * kapv;
            wq[tok] = p / s;
            ent_out[tok] = entv;
        }
    } else {
        if (lane < 32) {
            At[tok] = Av; ktc[tok] = kapv; vt[tok] = -0.5f * Av * kapv;
        }
    }
}

// --------------------------------------------------- fused GEMM + vMF epilogue
// C[4096,4096] = Qh*Th^T, 128x128 tile/block, 4 waves in 2x2 quadrants, 4x4
// grid of 16x16x32 f16 MFMA each. Staging: global_load_lds width=16, LDS
// unpadded 128 B/row with XOR chunk swizzle (chunk c of row r stored at
// c^(r&7)): lane-contiguous dest as the builtin requires, and ds_read_b128
// banks spread over all 32 (2-way = free). Swizzle term r&7 == (lane&15)&7 is
// a per-lane constant across i/kk.
__global__ void __launch_bounds__(256)
gemm_score(const _Float16* __restrict__ Qh, const _Float16* __restrict__ Th,
           const float* __restrict__ Apq, const float* __restrict__ kqc,
           const float* __restrict__ uq,  const float* __restrict__ wq,
           const float* __restrict__ At,  const float* __restrict__ ktc,
           const float* __restrict__ vt,  float* __restrict__ score_out) {
    __shared__ _Float16 Qs[128 * 64];   // 16 KB, swizzled
    __shared__ _Float16 Ts[128 * 64];
    int tid = threadIdx.x;
    int lane = tid & 63, wave = tid >> 6;
    int wr = wave >> 1, wc = wave & 1;
    int bx = blockIdx.x, by = blockIdx.y;

    floatx4 acc[4][4];
    #pragma unroll
    for (int i = 0; i < 4; ++i)
        #pragma unroll
        for (int j = 0; j < 4; ++j)
            acc[i][j] = (floatx4){0.f, 0.f, 0.f, 0.f};

    int l15 = lane & 15, lq = lane >> 4;
    int swz = l15 & 7;                      // ds_read chunk swizzle constant

    // staging constants: thread covers row rs, LDS chunk cl, global chunk cg
    int rs = tid >> 3;                      // + it*32
    int cl = tid & 7;
    int cg = cl ^ (rs & 7);                 // (it*32 doesn't change rs&7)
    const _Float16* gq = Qh + (size_t)(by * 128 + rs) * DDIM + cg * 8;
    const _Float16* gt = Th + (size_t)(bx * 128 + rs) * DDIM + cg * 8;
    // wave-uniform LDS byte base: rows it*32+wave*8, lane-contiguous 16B
    int lbase = wave * 1024;                // + it*4096

    for (int kk = 0; kk < 4; ++kk) {
        __syncthreads();
        #pragma unroll
        for (int it = 0; it < 4; ++it) {
            GLOAD_LDS16(gq + it * 32 * DDIM + kk * 64, (char*)Qs + lbase + it * 4096);
            GLOAD_LDS16(gt + it * 32 * DDIM + kk * 64, (char*)Ts + lbase + it * 4096);
        }
        __syncthreads();
        #pragma unroll
        for (int ks = 0; ks < 2; ++ks) {
            half8 a[4], b[4];
            int chunk = (ks * 4 + lq) ^ swz;      // logical k-chunk, swizzled
            #pragma unroll
            for (int i = 0; i < 4; ++i)
                a[i] = *(const half8*)(Qs + (wr * 64 + i * 16 + l15) * 64 + chunk * 8);
            #pragma unroll
            for (int j = 0; j < 4; ++j)
                b[j] = *(const half8*)(Ts + (wc * 64 + j * 16 + l15) * 64 + chunk * 8);
            #pragma unroll
            for (int i = 0; i < 4; ++i)
                #pragma unroll
                for (int j = 0; j < 4; ++j)
                    acc[i][j] = __builtin_amdgcn_mfma_f32_16x16x32_f16(a[i], b[j], acc[i][j], 0, 0, 0);
        }
    }

    int colbase = bx * 128 + wc * 64 + l15;
    int rowbase = by * 128 + wr * 64 + lq * 4;
    #pragma unroll
    for (int bi = 0; bi < 2; ++bi) {
        #pragma unroll
        for (int bj = 0; bj < 2; ++bj) {
            float part = 0.f;
            #pragma unroll
            for (int ii = 0; ii < 2; ++ii) {
                int i  = bi * 2 + ii;
                int rg = rowbase + i * 16;
                float mx[4] = {-INFINITY, -INFINITY, -INFINITY, -INFINITY};
                #pragma unroll
                for (int jj = 0; jj < 2; ++jj) {
                    int j  = bj * 2 + jj;
                    int cg2 = colbase + j * 16;
                    float at_ = At[cg2], kt_ = ktc[cg2], v_ = vt[cg2];
                    floatx4 sim = acc[i][j];
                    #pragma unroll
                    for (int rr = 0; rr < 4; ++rr) {
                        float sc = uq[rg + rr] + v_ +
                                   0.5f * (Apq[rg + rr] * kt_ + at_ * kqc[rg + rr]) * sim[rr];
                        mx[rr] = fmaxf(mx[rr], sc);
                    }
                }
                #pragma unroll
                for (int msk = 1; msk <= 8; msk <<= 1)
                    #pragma unroll
                    for (int rr = 0; rr < 4; ++rr)
                        mx[rr] = fmaxf(mx[rr], __shfl_xor(mx[rr], msk, 64));
                if (l15 == 0) {
                    #pragma unroll
                    for (int rr = 0; rr < 4; ++rr)
                        part += wq[rg + rr] * mx[rr];
                }
            }
            part += __shfl_xor(part, 16, 64);
            part += __shfl_xor(part, 32, 64);
            if (lane == 0) {
                int b = by * 4 + wr * 2 + bi;
                int n = bx * 4 + wc * 2 + bj;
                score_out[b * 128 + n] = part;
            }
        }
    }
}

// ------------------------------------------- logits, log-softmax over n, loss
__global__ void softmax_loss(const float* __restrict__ score, const float* __restrict__ temp_p,
                             float* __restrict__ logits, float* __restrict__ loss) {
    __shared__ float sc[128 * 129];
    __shared__ float part[2];
    int tid = threadIdx.x;    // 0..127
    float temp = fmaxf(temp_p[0], 1e-6f);
    float inv = 1.0f / temp;

    for (int idx = tid; idx < 4096; idx += 128) {
        float4 v = *(const float4*)(score + idx * 4);
        int r = (idx * 4) >> 7, c = (idx * 4) & 127;
        float* p = sc + r * 129 + c;
        p[0] = v.x; p[1] = v.y; p[2] = v.z; p[3] = v.w;
    }
    __syncthreads();

    int b = tid;
    float m = -INFINITY;
    for (int j = 0; j < 128; ++j) m = fmaxf(m, sc[b * 129 + j] * inv);
    float s = 0.f;
    for (int j = 0; j < 128; ++j) s += expf(sc[b * 129 + j] * inv - m);
    float lse = m + logf(s);
    float le  = lse - sc[b * 129 + b] * inv;

    for (int idx = tid; idx < 4096; idx += 128) {
        int r = (idx * 4) >> 7, c = (idx * 4) & 127;
        float* p = sc + r * 129 + c;
        float4 v = {p[0] * inv, p[1] * inv, p[2] * inv, p[3] * inv};
        *(float4*)(logits + idx * 4) = v;
    }

    float x = le;
    #pragma unroll
    for (int off = 1; off < 64; off <<= 1) x += __shfl_xor(x, off, 64);
    if ((tid & 63) == 0) part[tid >> 6] = x;
    __syncthreads();
    if (tid == 0) loss[0] = (part[0] + part[1]) * (1.0f / 128.0f);
}

// ---------------------------------------------------------------------- launch
extern "C" void kernel_launch(void* const* d_in, const int* in_sizes, int n_in,
                              void* d_out, int out_size, void* d_ws, size_t ws_size,
                              hipStream_t stream) {
    const float* q    = (const float*)d_in[0];   // (128,32,256)
    const float* kq   = (const float*)d_in[1];   // (128,32)
    const float* t    = (const float*)d_in[2];   // (128,32,256)
    const float* kt   = (const float*)d_in[3];   // (128,32)
    const float* temp = (const float*)d_in[4];   // scalar

    float* out    = (float*)d_out;
    float* loss   = out;                 // [1]
    float* logits = out + 1;             // [128*128]
    float* score  = out + 1 + 16384;     // [128*128]
    float* ent    = out + 1 + 32768;     // [128*32]

    char* ws = (char*)d_ws;
    _Float16* Qh = (_Float16*)(ws);
    _Float16* Th = (_Float16*)(ws + (1 << 21));
    float* stats = (float*)(ws + (1 << 22));
    float *Apq = stats,          *kqc = stats + 4096, *uq = stats + 8192,
          *wq  = stats + 12288,  *At  = stats + 16384, *ktc = stats + 20480,
          *vt  = stats + 24576;

    prep<<<2112, 256, 0, stream>>>(q, t, Qh, Th, kq, kt,
                                   Apq, kqc, uq, wq, At, ktc, vt, ent);
    dim3 g(32, 32);
    gemm_score<<<g, 256, 0, stream>>>(Qh, Th, Apq, kqc, uq, wq, At, ktc, vt, score);
    softmax_loss<<<1, 128, 0, stream>>>(score, temp, logits, loss);
}

// Round 4
// 128.922 us; speedup vs baseline: 1.0767x; 1.0050x over previous
//
#include <hip/hip_runtime.h>
#include <math.h>

typedef _Float16 half8  __attribute__((ext_vector_type(8)));
typedef _Float16 half4v __attribute__((ext_vector_type(4)));
typedef float    floatx4 __attribute__((ext_vector_type(4)));

#define DDIM 256

// async global->LDS, 16B per lane; LDS dest = wave-uniform base + lane*16
#define GLOAD_LDS16(g, l) \
    __builtin_amdgcn_global_load_lds((const __attribute__((address_space(1))) void*)(g), \
                                     (__attribute__((address_space(3))) void*)(l), 16, 0, 0)

// ------------------------------------------------------------ fused prep
// blocks [0,2048): fp32->fp16 convert of q (first 1024) and t (next 1024)
// blocks [2048,2112): per-token vMF stats, 4 waves/block, one 32-token row/wave.
__global__ void prep(const float* __restrict__ q, const float* __restrict__ t,
                     _Float16* __restrict__ Qh, _Float16* __restrict__ Th,
                     const float* __restrict__ kq, const float* __restrict__ kt,
                     float* __restrict__ Apq, float* __restrict__ kqc, float* __restrict__ uq,
                     float* __restrict__ wq,
                     float* __restrict__ At,  float* __restrict__ ktc, float* __restrict__ vt,
                     float* __restrict__ ent_out) {
    int b = blockIdx.x;
    if (b < 2048) {
        const float* src = (b < 1024) ? q : t;
        _Float16*    dst = (b < 1024) ? Qh : Th;
        int i = ((b & 1023) * 1024) + threadIdx.x * 4;
        float4 v = *(const float4*)(src + i);
        half4v h;
        h[0] = (_Float16)v.x; h[1] = (_Float16)v.y; h[2] = (_Float16)v.z; h[3] = (_Float16)v.w;
        *(half4v*)(dst + i) = h;
        return;
    }
    int lane = threadIdx.x & 63;
    int row  = (b - 2048) * 4 + (threadIdx.x >> 6);   // 0..255
    bool isQ = row < 128;
    const float* ksrc = isQ ? (kq + row * 32) : (kt + (row - 128) * 32);

    // lgamma(k+1)+lgamma(k+128) = lgamma(128) + prefix_sum[log j + log(j+127)]
    float a = 0.f;
    if (lane >= 1 && lane < 50) a = logf((float)lane) + logf((float)(lane + 127));
    #pragma unroll
    for (int off = 1; off < 64; off <<= 1) {
        float tmp = __shfl_up(a, off, 64);
        if (lane >= off) a += tmp;
    }
    const float slg   = 491.5534482233f + a;
    const float lk128 = logf((float)(lane + 128));
    const float c0k   = (float)(2 * lane + 127);
    const float c1k   = (float)(2 * lane + 128);
    const bool  valid = lane < 50;

    float entv = 0.f, Av = 0.f, kapv = 0.f;
    for (int i = 0; i < 32; ++i) {
        float kap  = fmaxf(ksrc[i], 1e-6f);
        float lkap = logf(kap);
        float lx   = lkap - 0.6931471805599453f;    // log(kap/2)
        float lc0 = valid ? c0k * lx - slg         : -INFINITY;
        float lc1 = valid ? c1k * lx - slg - lk128 : -INFINITY;
        float m0 = lc0, m1 = lc1;
        #pragma unroll
        for (int off = 1; off < 64; off <<= 1) {
            m0 = fmaxf(m0, __shfl_xor(m0, off, 64));
            m1 = fmaxf(m1, __shfl_xor(m1, off, 64));
        }
        float e0 = valid ? expf(lc0 - m0) : 0.f;
        float e1 = valid ? expf(lc1 - m1) : 0.f;
        #pragma unroll
        for (int off = 1; off < 64; off <<= 1) {
            e0 += __shfl_xor(e0, off, 64);
            e1 += __shfl_xor(e1, off, 64);
        }
        float logI0 = m0 + logf(e0);   // log I_127(kap)
        float logI1 = m1 + logf(e1);   // log I_128(kap)

        float A = expf(fminf(fmaxf(logI1 - logI0, -60.f), 0.f));
        A = fminf(fmaxf(A, 1e-8f), 1.f - 1e-6f);
        float logC = 127.f * lkap - 235.2482644983962f - logI0;  // 128*log(2pi)
        float e = -logC - kap * A;
        if (lane == i) { entv = e; Av = A; kapv = kap; }
    }

    int tok = (isQ ? row : row - 128) * 32 + lane;
    if (isQ) {
        float x = (lane < 32) ? -2.0f * entv : -INFINITY;
        float m = x;
        #pragma unroll
        for (int off = 1; off < 64; off <<= 1) m = fmaxf(m, __shfl_xor(m, off, 64));
        float p = (lane < 32) ? expf(x - m) : 0.f;
        float s = p;
        #pragma unroll
        for (int off = 1; off < 64; off <<= 1) s += __shfl_xor(s, off, 64);
        if (lane < 32) {
            Apq[tok] = Av; kqc[tok] = kapv; uq[tok] = -0.5f * Av * kapv;
            wq[tok] = p / s;
            ent_out[tok] = entv;
        }
    } else {
        if (lane < 32) {
            At[tok] = Av; ktc[tok] = kapv; vt[tok] = -0.5f * Av * kapv;
        }
    }
}

// --------------------------------------------------- fused GEMM + vMF epilogue
// 128x128 tile/block, 4 waves in 2x2 quadrants, 4x4 grid of 16x16x32 f16 MFMA.
// DOUBLE-BUFFERED: loads for chunk kk+1 are issued right after the barrier of
// chunk kk, so the vmcnt(0) drain at the NEXT barrier waits on loads that have
// had a full chunk's compute (~600-1200 cyc) to land -> steady-state stall ~0.
// One barrier per chunk. XOR chunk swizzle (c^(r&7)) keeps global_load_lds's
// lane-contiguous dest while spreading ds_read_b128 banks (2-way = free).
__global__ void __launch_bounds__(256)
gemm_score(const _Float16* __restrict__ Qh, const _Float16* __restrict__ Th,
           const float* __restrict__ Apq, const float* __restrict__ kqc,
           const float* __restrict__ uq,  const float* __restrict__ wq,
           const float* __restrict__ At,  const float* __restrict__ ktc,
           const float* __restrict__ vt,  float* __restrict__ score_out) {
    __shared__ _Float16 Qs[2][128 * 64];   // 2 x 16 KB
    __shared__ _Float16 Ts[2][128 * 64];
    int tid = threadIdx.x;
    int lane = tid & 63, wave = tid >> 6;
    int wr = wave >> 1, wc = wave & 1;
    int bx = blockIdx.x, by = blockIdx.y;

    floatx4 acc[4][4];
    #pragma unroll
    for (int i = 0; i < 4; ++i)
        #pragma unroll
        for (int j = 0; j < 4; ++j)
            acc[i][j] = (floatx4){0.f, 0.f, 0.f, 0.f};

    int l15 = lane & 15, lq = lane >> 4;
    int swz = l15 & 7;

    // staging: thread covers row rs (+it*32), LDS chunk cl, global chunk cg
    int rs = tid >> 3;
    int cl = tid & 7;
    int cg = cl ^ (rs & 7);
    const _Float16* gq = Qh + (size_t)(by * 128 + rs) * DDIM + cg * 8;
    const _Float16* gt = Th + (size_t)(bx * 128 + rs) * DDIM + cg * 8;
    int lbase = wave * 1024;               // LDS byte base (+it*4096)

    // prologue: chunk 0 -> buffer 0 (only exposed staging wait in the kernel)
    #pragma unroll
    for (int it = 0; it < 4; ++it) {
        GLOAD_LDS16(gq + it * 32 * DDIM, (char*)Qs[0] + lbase + it * 4096);
        GLOAD_LDS16(gt + it * 32 * DDIM, (char*)Ts[0] + lbase + it * 4096);
    }

    #pragma unroll
    for (int kk = 0; kk < 4; ++kk) {
        int p = kk & 1;
        // drains: chunk-kk loads (issued one iteration ago) + last ds_reads
        __syncthreads();
        if (kk < 3) {                       // prefetch chunk kk+1 into other buf
            #pragma unroll
            for (int it = 0; it < 4; ++it) {
                GLOAD_LDS16(gq + it * 32 * DDIM + (kk + 1) * 64,
                            (char*)Qs[p ^ 1] + lbase + it * 4096);
                GLOAD_LDS16(gt + it * 32 * DDIM + (kk + 1) * 64,
                            (char*)Ts[p ^ 1] + lbase + it * 4096);
            }
        }
        #pragma unroll
        for (int ks = 0; ks < 2; ++ks) {
            half8 a[4], b[4];
            int chunk = (ks * 4 + lq) ^ swz;
            #pragma unroll
            for (int i = 0; i < 4; ++i)
                a[i] = *(const half8*)(Qs[p] + (wr * 64 + i * 16 + l15) * 64 + chunk * 8);
            #pragma unroll
            for (int j = 0; j < 4; ++j)
                b[j] = *(const half8*)(Ts[p] + (wc * 64 + j * 16 + l15) * 64 + chunk * 8);
            #pragma unroll
            for (int i = 0; i < 4; ++i)
                #pragma unroll
                for (int j = 0; j < 4; ++j)
                    acc[i][j] = __builtin_amdgcn_mfma_f32_16x16x32_f16(a[i], b[j], acc[i][j], 0, 0, 0);
        }
    }

    // ---- epilogue: max over 32 t-cols, weighted sum over 32 q-rows
    int colbase = bx * 128 + wc * 64 + l15;
    int rowbase = by * 128 + wr * 64 + lq * 4;
    #pragma unroll
    for (int bi = 0; bi < 2; ++bi) {
        #pragma unroll
        for (int bj = 0; bj < 2; ++bj) {
            float part = 0.f;
            #pragma unroll
            for (int ii = 0; ii < 2; ++ii) {
                int i  = bi * 2 + ii;
                int rg = rowbase + i * 16;
                float mx[4] = {-INFINITY, -INFINITY, -INFINITY, -INFINITY};
                #pragma unroll
                for (int jj = 0; jj < 2; ++jj) {
                    int j  = bj * 2 + jj;
                    int cg2 = colbase + j * 16;
                    float at_ = At[cg2], kt_ = ktc[cg2], v_ = vt[cg2];
                    floatx4 sim = acc[i][j];
                    #pragma unroll
                    for (int rr = 0; rr < 4; ++rr) {
                        float sc = uq[rg + rr] + v_ +
                                   0.5f * (Apq[rg + rr] * kt_ + at_ * kqc[rg + rr]) * sim[rr];
                        mx[rr] = fmaxf(mx[rr], sc);
                    }
                }
                #pragma unroll
                for (int msk = 1; msk <= 8; msk <<= 1)
                    #pragma unroll
                    for (int rr = 0; rr < 4; ++rr)
                        mx[rr] = fmaxf(mx[rr], __shfl_xor(mx[rr], msk, 64));
                if (l15 == 0) {
                    #pragma unroll
                    for (int rr = 0; rr < 4; ++rr)
                        part += wq[rg + rr] * mx[rr];
                }
            }
            part += __shfl_xor(part, 16, 64);
            part += __shfl_xor(part, 32, 64);
            if (lane == 0) {
                int b = by * 4 + wr * 2 + bi;
                int n = bx * 4 + wc * 2 + bj;
                score_out[b * 128 + n] = part;
            }
        }
    }
}

// ------------------------------------------- logits, log-softmax over n, loss
__global__ void softmax_loss(const float* __restrict__ score, const float* __restrict__ temp_p,
                             float* __restrict__ logits, float* __restrict__ loss) {
    __shared__ float sc[128 * 129];
    __shared__ float part[2];
    int tid = threadIdx.x;    // 0..127
    float temp = fmaxf(temp_p[0], 1e-6f);
    float inv = 1.0f / temp;

    for (int idx = tid; idx < 4096; idx += 128) {
        float4 v = *(const float4*)(score + idx * 4);
        int r = (idx * 4) >> 7, c = (idx * 4) & 127;
        float* p = sc + r * 129 + c;
        p[0] = v.x; p[1] = v.y; p[2] = v.z; p[3] = v.w;
    }
    __syncthreads();

    int b = tid;
    float m = -INFINITY;
    for (int j = 0; j < 128; ++j) m = fmaxf(m, sc[b * 129 + j] * inv);
    float s = 0.f;
    for (int j = 0; j < 128; ++j) s += expf(sc[b * 129 + j] * inv - m);
    float lse = m + logf(s);
    float le  = lse - sc[b * 129 + b] * inv;

    for (int idx = tid; idx < 4096; idx += 128) {
        int r = (idx * 4) >> 7, c = (idx * 4) & 127;
        float* p = sc + r * 129 + c;
        float4 v = {p[0] * inv, p[1] * inv, p[2] * inv, p[3] * inv};
        *(float4*)(logits + idx * 4) = v;
    }

    float x = le;
    #pragma unroll
    for (int off = 1; off < 64; off <<= 1) x += __shfl_xor(x, off, 64);
    if ((tid & 63) == 0) part[tid >> 6] = x;
    __syncthreads();
    if (tid == 0) loss[0] = (part[0] + part[1]) * (1.0f / 128.0f);
}

// ---------------------------------------------------------------------- launch
extern "C" void kernel_launch(void* const* d_in, const int* in_sizes, int n_in,
                              void* d_out, int out_size, void* d_ws, size_t ws_size,
                              hipStream_t stream) {
    const float* q    = (const float*)d_in[0];   // (128,32,256)
    const float* kq   = (const float*)d_in[1];   // (128,32)
    const float* t    = (const float*)d_in[2];   // (128,32,256)
    const float* kt   = (const float*)d_in[3];   // (128,32)
    const float* temp = (const float*)d_in[4];   // scalar

    float* out    = (float*)d_out;
    float* loss   = out;                 // [1]
    float* logits = out + 1;             // [128*128]
    float* score  = out + 1 + 16384;     // [128*128]
    float* ent    = out + 1 + 32768;     // [128*32]

    char* ws = (char*)d_ws;
    _Float16* Qh = (_Float16*)(ws);
    _Float16* Th = (_Float16*)(ws + (1 << 21));
    float* stats = (float*)(ws + (1 << 22));
    float *Apq = stats,          *kqc = stats + 4096, *uq = stats + 8192,
          *wq  = stats + 12288,  *At  = stats + 16384, *ktc = stats + 20480,
          *vt  = stats + 24576;

    prep<<<2112, 256, 0, stream>>>(q, t, Qh, Th, kq, kt,
                                   Apq, kqc, uq, wq, At, ktc, vt, ent);
    dim3 g(32, 32);
    gemm_score<<<g, 256, 0, stream>>>(Qh, Th, Apq, kqc, uq, wq, At, ktc, vt, score);
    softmax_loss<<<1, 128, 0, stream>>>(score, temp, logits, loss);
}